// Round 13
// baseline (100.452 us; speedup 1.0000x reference)
//
#include <hip/hip_runtime.h>
#include <hip/hip_bf16.h>

// Problem: B=2, C=64, H=W=96 -> M=N=9216
//   scores[b,m,n] = sum_c yi[b,c,m]*pi[b,c,n] ; weight = softmax over m
//   out[b,c,n]    = sum_m yi[b,c,m]*weight[b,m,n]
// == flash attention with Q=pi (queries n), K=V=yi (keys m), head dim 64.
//
// R13: R12's pipes still SUM (26 MFMA + 36 VALU + 26 LDS ~= 89 wall) because
// the grid was load-imbalanced: 1152 blocks / 256 CU = 4.5 per CU against
// 3-resident (registers) -> round 2 runs half-empty; measured Occupancy 23%
// vs 37.5% ceiling matches the two-round average. Fix: S=16 -> 2304 blocks
// = exactly 9/CU = three FULL rounds of 3 (tpb=9). Partials double
// (37->75MB) but the reduce is L2-resident and cheap (~+5us). XCD decode
// generalized (g = xcd+8*(slot/NBX); split = g%S, b = g/S; bijective for
// S=8,16 -- enumerated). Tile loop byte-identical to R12 (verified).
// absmax watch-item: 0.084 @ R12; if >0.09125 revert to 3-product QK.

#define CC 64
#define MM 9216
#define BB 2
#define WAVES 4
#define NPW 32                 // query columns per wave
#define NBLK (WAVES * NPW)     // 128
#define NBX (MM / NBLK)        // 72
#define MTILE 64
#define NT (MM / MTILE)        // 144

typedef __bf16 bf16x8 __attribute__((ext_vector_type(8)));
typedef float f32x16 __attribute__((ext_vector_type(16)));
typedef unsigned int u32x4 __attribute__((ext_vector_type(4)));

// row-XOR swizzle on 8-element groups (verified R2-R12)
__device__ __forceinline__ int swz(int r) { return ((r >> 1) ^ (r >> 4)) & 7; }

__device__ __forceinline__ void gld16(const void* gsrc, void* ldst) {
    __builtin_amdgcn_global_load_lds(
        (const __attribute__((address_space(1))) void*)gsrc,
        (__attribute__((address_space(3))) void*)ldst, 16, 0, 0);
}

// native 2^x
__device__ __forceinline__ float fexp2(float x) {
#if __has_builtin(__builtin_amdgcn_exp2f)
    return __builtin_amdgcn_exp2f(x);
#else
    return exp2f(x);
#endif
}

// pack two f32 -> dword of two bf16
__device__ __forceinline__ unsigned int pack2(float a, float b) {
    const unsigned short ua = __builtin_bit_cast(unsigned short, (__bf16)a);
    const unsigned short ub = __builtin_bit_cast(unsigned short, (__bf16)b);
    return (unsigned int)ua | ((unsigned int)ub << 16);
}

// ---------------- prepass: bake conversion + transpose + swizzle ----------------
// kt[b][m][c ^ (swz(m&63)<<3)]  (m-major: one 8KB contiguous block/tile)
// vt[b][c][t*64 + ((m&63) ^ (swz(c)<<3))]
__global__ __launch_bounds__(256)
void prepass(const float* __restrict__ yi, __bf16* __restrict__ kt,
             __bf16* __restrict__ vt)
{
    const int t = blockIdx.x;     // key tile 0..143
    const int b = blockIdx.y;
    const int tid = threadIdx.x;  // 256
    const float* src = yi + (size_t)b * CC * MM;

    for (int tsk = tid; tsk < 512; tsk += 256) {
        const int m = tsk & 63, g = tsk >> 6;
        const int m_abs = t * 64 + m;
        bf16x8 hh;
        #pragma unroll
        for (int j = 0; j < 8; ++j)
            hh[j] = (__bf16)src[(size_t)(g * 8 + j) * MM + m_abs];
        *reinterpret_cast<bf16x8*>(
            kt + (size_t)(b * MM + m_abs) * 64 + ((g ^ swz(m)) << 3)) = hh;
    }
    for (int tsk = tid; tsk < 512; tsk += 256) {
        const int c = tsk & 63, gm = tsk >> 6;
        const float* p = src + (size_t)c * MM + t * 64 + gm * 8;
        bf16x8 hh;
        #pragma unroll
        for (int j = 0; j < 8; ++j) hh[j] = (__bf16)p[j];
        *reinterpret_cast<bf16x8*>(
            vt + (size_t)(b * CC + c) * MM + t * 64 + ((gm ^ swz(c)) << 3)) = hh;
    }
}

// ---------------- main flash kernel (32x32x16, raw-2^s softmax, no max) ----------
template<bool FINAL>
__global__ __launch_bounds__(WAVES * 64, 2)
void attn_main(const __bf16* __restrict__ kt, const __bf16* __restrict__ vt,
               const float* __restrict__ pi,
               float* __restrict__ out, float* __restrict__ opart,
               float* __restrict__ lpart, const int nsplits)
{
    __shared__ __align__(16) __bf16 k_sm[2][MTILE][64];   // 16KB (double-buffered)
    __shared__ __align__(16) __bf16 v_sm[2][CC][64];      // 16KB  -> 32KB total

    const int tid  = threadIdx.x;
    const int lane = tid & 63;
    const int wave = tid >> 6;     // 0..3
    const int l31  = lane & 31;
    const int hi   = lane >> 5;    // 0/1

    // ---- block decode: XCD-locality map for 1D launches, else plain 3D ----
    int bx, split, b;
    if (gridDim.y == 1 && !FINAL) {
        const int bid = blockIdx.x;              // 0 .. 2*S*NBX-1
        const int xcd = bid & 7, slot = bid >> 3;
        bx = slot % NBX;
        const int g = xcd + 8 * (slot / NBX);    // group 0..2S-1, one XCD each
        split = g % nsplits;
        b     = g / nsplits;
    } else {
        bx = blockIdx.x; split = blockIdx.y; b = blockIdx.z;
    }

    const int tpb = NT / nsplits;
    const int t0s = split * tpb;
    const int n0  = bx * NBLK + wave * NPW;
    const int n_g = n0 + l31;

    // ---- async staging: 16 x 1KB chunks, 4 per wave, linear LDS dest ----
    auto stage = [&](int bb, int t) {
        const size_t kbase = (size_t)(b * MM + t * 64) * 64;   // elements
        #pragma unroll
        for (int q = 0; q < 4; ++q) {
            const int ch = wave * 4 + q;         // wave-uniform, 0..15
            if (ch < 8) {
                gld16(kt + kbase + ch * 512 + lane * 8,
                      (char*)(&k_sm[bb][0][0]) + ch * 1024);
            } else {
                const int j = ch - 8;
                const int c = j * 8 + (lane >> 3);
                gld16(vt + (size_t)(b * CC + c) * MM + t * 64 + (lane & 7) * 8,
                      (char*)(&v_sm[bb][0][0]) + j * 1024);
            }
        }
    };

    stage(0, t0s);   // DMA in flight while Q loads below

    // ---- Q fragments (hi/lo split), log2e folded in: s = log2e * (q.k) ----
    const float LOG2E = 1.4426950408889634f;
    bf16x8 qh[4], ql[4];
    {
        const float* qb = pi + (size_t)b * CC * MM + n_g;
        #pragma unroll
        for (int ks = 0; ks < 4; ++ks)
            #pragma unroll
            for (int j = 0; j < 8; ++j) {
                const float f = qb[(size_t)(ks * 16 + hi * 8 + j) * MM] * LOG2E;
                const __bf16 h = (__bf16)f;
                qh[ks][j] = h;
                ql[ks][j] = (__bf16)(f - (float)h);
            }
    }

    f32x16 o0, o1;
    #pragma unroll
    for (int r = 0; r < 16; ++r) { o0[r] = 0.f; o1[r] = 0.f; }
    float run_l = 0.f;

    const int sx0 = swz(l31) << 3;        // row swizzle, rows 0..31
    const int sx1 = swz(32 + l31) << 3;   // rows 32..63

    __syncthreads();   // vmcnt drained -> buf0 ready
    int buf = 0;

    for (int it = 0; it < tpb; ++it) {
        // ---- prefetch next tile into the other buffer; drains under compute ----
        if (it + 1 < tpb) stage(buf ^ 1, t0s + it + 1);

        // ---- QK^T: S[m 64][n 32], 2-product split-bf16 (K single-bf16) ----
        f32x16 s0, s1;
        #pragma unroll
        for (int r = 0; r < 16; ++r) { s0[r] = 0.f; s1[r] = 0.f; }
        __builtin_amdgcn_s_setprio(1);
        #pragma unroll
        for (int ks = 0; ks < 4; ++ks) {
            const int cb = ks * 16 + hi * 8;
            const bf16x8 a0 = *(const bf16x8*)&k_sm[buf][l31][cb ^ sx0];
            const bf16x8 a1 = *(const bf16x8*)&k_sm[buf][32 + l31][cb ^ sx1];
            s0 = __builtin_amdgcn_mfma_f32_32x32x16_bf16(a0, qh[ks], s0, 0, 0, 0);
            s1 = __builtin_amdgcn_mfma_f32_32x32x16_bf16(a1, qh[ks], s1, 0, 0, 0);
            s0 = __builtin_amdgcn_mfma_f32_32x32x16_bf16(a0, ql[ks], s0, 0, 0, 0);
            s1 = __builtin_amdgcn_mfma_f32_32x32x16_bf16(a1, ql[ks], s1, 0, 0, 0);
        }
        __builtin_amdgcn_s_setprio(0);

        // ---- raw softmax numerators: P = 2^s (no max tracking -- see R12) ----
        float ps[8];
        #pragma unroll
        for (int r = 0; r < 8; ++r) {
            s0[r]     = fexp2(s0[r]);
            s0[r + 8] = fexp2(s0[r + 8]);
            s1[r]     = fexp2(s1[r]);
            s1[r + 8] = fexp2(s1[r + 8]);
            ps[r] = (s0[r] + s0[r + 8]) + (s1[r] + s1[r + 8]);
        }
        float psum = ((ps[0] + ps[1]) + (ps[2] + ps[3])) +
                     ((ps[4] + ps[5]) + (ps[6] + ps[7]));
        psum += __shfl_xor(psum, 32);               // R6-verified reduce
        run_l += psum;

        // ---- pack P to bf16 dwords: X[mt][q][d] = pack(p[4q+2d], p[4q+2d+1]) ----
        unsigned int X[2][4][2];
        #pragma unroll
        for (int q = 0; q < 4; ++q)
            #pragma unroll
            for (int d = 0; d < 2; ++d) {
                X[0][q][d] = pack2(s0[4 * q + 2 * d], s0[4 * q + 2 * d + 1]);
                X[1][q][d] = pack2(s1[4 * q + 2 * d], s1[4 * q + 2 * d + 1]);
            }

        // ---- PV: B-frag via shfl_xor + selects (R6-verified exchange) ----
        __builtin_amdgcn_s_setprio(1);
        #pragma unroll
        for (int ks = 0; ks < 4; ++ks) {
            const int mt = ks >> 1, e = ks & 1;
            const unsigned int A0 = X[mt][2 * e][0],     A1 = X[mt][2 * e][1];
            const unsigned int B0 = X[mt][2 * e + 1][0], B1 = X[mt][2 * e + 1][1];
            // partner (hi=0 lane) needs my A-pair; partner (hi=1) needs my B-pair
            const unsigned int r0 = __shfl_xor(hi ? A0 : B0, 32);
            const unsigned int r1 = __shfl_xor(hi ? A1 : B1, 32);
            u32x4 w;
            w.x = hi ? r0 : A0;   // j=0..1
            w.y = hi ? r1 : A1;   // j=2..3
            w.z = hi ? B0 : r0;   // j=4..5
            w.w = hi ? B1 : r1;   // j=6..7
            const bf16x8 bp = __builtin_bit_cast(bf16x8, w);

            const int cb = ks * 16 + hi * 8;
            const bf16x8 av0 = *(const bf16x8*)&v_sm[buf][l31][cb ^ sx0];
            const bf16x8 av1 = *(const bf16x8*)&v_sm[buf][32 + l31][cb ^ sx1];
            o0 = __builtin_amdgcn_mfma_f32_32x32x16_bf16(av0, bp, o0, 0, 0, 0);
            o1 = __builtin_amdgcn_mfma_f32_32x32x16_bf16(av1, bp, o1, 0, 0, 0);
        }
        __builtin_amdgcn_s_setprio(0);

        // ONE barrier: all waves done reading buf (it can be overwritten next
        // iter) AND the pre-barrier vmcnt drain publishes buf^1 for next iter.
        __syncthreads();
        buf ^= 1;
    }

    // ---- epilogue: c = (r&3) + 8*(r>>2) + 4*hi ----
    if (FINAL) {
        const float inv = 1.f / run_l;
        #pragma unroll
        for (int r = 0; r < 16; ++r) {
            const int cl = (r & 3) + 8 * (r >> 2) + 4 * hi;
            out[((size_t)b * CC + cl) * MM + n_g]      = o0[r] * inv;
            out[((size_t)b * CC + cl + 32) * MM + n_g] = o1[r] * inv;
        }
    } else {
        const size_t pbase = (size_t)(b * nsplits + split) * CC * MM;
        #pragma unroll
        for (int r = 0; r < 16; ++r) {
            const int cl = (r & 3) + 8 * (r >> 2) + 4 * hi;
            opart[pbase + (size_t)cl * MM + n_g]        = o0[r];
            opart[pbase + (size_t)(cl + 32) * MM + n_g] = o1[r];
        }
        if (hi == 0)   // lanes n and n+32 hold identical run_l
            lpart[(size_t)(b * nsplits + split) * MM + n_g] = run_l;
    }
}

// out = sum_s O_s / sum_s l_s  -- pure sums, no exp/max (shared zero baseline)
template<int S>
__global__ __launch_bounds__(256)
void attn_reduce4(const float* __restrict__ opart, const float* __restrict__ lpart,
                  float* __restrict__ out)
{
    const int t = blockIdx.x * 256 + threadIdx.x;
    if (t >= BB * CC * MM / 4) return;
    const int n  = (t * 4) % MM;
    const int bc = (t * 4) / MM;
    const int b  = bc / CC;
    const int c  = bc - b * CC;

    float L[4]   = {0.f, 0.f, 0.f, 0.f};
    float acc[4] = {0.f, 0.f, 0.f, 0.f};
    #pragma unroll
    for (int s = 0; s < S; ++s) {
        const float4 l4 = *reinterpret_cast<const float4*>(
            &lpart[(size_t)(b * S + s) * MM + n]);
        L[0] += l4.x; L[1] += l4.y; L[2] += l4.z; L[3] += l4.w;
        const float4 o4 = *reinterpret_cast<const float4*>(
            &opart[((size_t)(b * S + s) * CC + c) * MM + n]);
        acc[0] += o4.x; acc[1] += o4.y; acc[2] += o4.z; acc[3] += o4.w;
    }
    float4 r;
    r.x = acc[0] / L[0]; r.y = acc[1] / L[1];
    r.z = acc[2] / L[2]; r.w = acc[3] / L[3];
    *reinterpret_cast<float4*>(&out[(size_t)t * 4]) = r;
}

extern "C" void kernel_launch(void* const* d_in, const int* in_sizes, int n_in,
                              void* d_out, int out_size, void* d_ws, size_t ws_size,
                              hipStream_t stream) {
    const float* yi = (const float*)d_in[0];   // feature_yi (K = V)
    const float* pi = (const float*)d_in[1];   // feature_pi (Q)
    float* out = (float*)d_out;

    const size_t kelems = (size_t)BB * MM * 64;              // kt elements
    const size_t velems = (size_t)BB * CC * MM;              // vt elements
    const size_t preB   = (kelems + velems) * 2;             // ~4.7 MB
    auto need = [&](int s) -> size_t {
        return preB + (size_t)BB * s * CC * MM * 4 + (size_t)BB * s * MM * 4;
    };

    int S = 1;
    if (d_ws) {
        if (ws_size >= need(16))     S = 16;  // 2304 blocks = 9/CU: 3 full rounds of 3
        else if (ws_size >= need(8)) S = 8;
        else if (ws_size >= need(4)) S = 4;
        else if (ws_size >= need(2)) S = 2;
    }

    if (S == 1) {
        if (!d_ws || ws_size < preB) return;
        __bf16* kt = (__bf16*)d_ws;
        __bf16* vt = kt + kelems;
        prepass<<<dim3(NT, BB), dim3(256), 0, stream>>>(yi, kt, vt);
        attn_main<true><<<dim3(NBX, 1, BB), dim3(WAVES * 64), 0, stream>>>(
            kt, vt, pi, out, out, out, 1);
        return;
    }

    __bf16* kt   = (__bf16*)d_ws;
    __bf16* vt   = kt + kelems;
    float* opart = (float*)(vt + velems);
    float* lp    = opart + (size_t)BB * S * CC * MM;

    prepass<<<dim3(NT, BB), dim3(256), 0, stream>>>(yi, kt, vt);

    if (S == 16 || S == 8) {
        // 1D grid, XCD-locality mapping: all NBX n-blocks of a (b,split)
        // group land on one XCD (g = xcd + 8*(slot/NBX); bijective).
        attn_main<false><<<dim3(NBX * 2 * S), dim3(WAVES * 64), 0, stream>>>(
            kt, vt, pi, out, opart, lp, S);
    } else {
        attn_main<false><<<dim3(NBX, S, BB), dim3(WAVES * 64), 0, stream>>>(
            kt, vt, pi, out, opart, lp, S);
    }

    const int total4 = BB * CC * MM / 4;
    const dim3 rg((total4 + 255) / 256), rb(256);
    if (S == 16)     attn_reduce4<16><<<rg, rb, 0, stream>>>(opart, lp, out);
    else if (S == 8) attn_reduce4<8><<<rg, rb, 0, stream>>>(opart, lp, out);
    else if (S == 4) attn_reduce4<4><<<rg, rb, 0, stream>>>(opart, lp, out);
    else             attn_reduce4<2><<<rg, rb, 0, stream>>>(opart, lp, out);
}

// Round 14
// 92.962 us; speedup vs baseline: 1.0806x; 1.0806x over previous
//
#include <hip/hip_runtime.h>
#include <hip/hip_bf16.h>

// Problem: B=2, C=64, H=W=96 -> M=N=9216
//   scores[b,m,n] = sum_c yi[b,c,m]*pi[b,c,n] ; weight = softmax over m
//   out[b,c,n]    = sum_m yi[b,c,m]*weight[b,m,n]
// == flash attention with Q=pi (queries n), K=V=yi (keys m), head dim 64.
//
// R14: R13's S=16 helped main (-4us) but doubled partials cost the reduce
// +7us -> net regression; revert to S=8 (best total, R12 = 97.7us).
// New lever: PV B-frag exchange via permlane32_swap (VALU) instead of
// shfl_xor+selects (ds_bpermute on the LDS pipe -- the biggest pipe).
// R7's failure was ONLY the aliased swap(v,v) in the reduce; the PV
// mapping re-derived from ISA semantics matches the shfl version exactly:
//   rA = swap(A0,B0): rA[0] = {A0own | B0_partner} = w.x (both lanes ok)
//                     rA[1] = {A0_partner | B0own} = w.z
// Distinct operands -> no aliasing. Replaces 8 LDS ops + 16 cndmask with
// 8 VALU ops per wave-tile. psum reduce keeps verified shfl_xor.
// Everything else byte-identical to R12 (verified, absmax 0.08398438).

#define CC 64
#define MM 9216
#define BB 2
#define WAVES 4
#define NPW 32                 // query columns per wave
#define NBLK (WAVES * NPW)     // 128
#define NBX (MM / NBLK)        // 72
#define MTILE 64
#define NT (MM / MTILE)        // 144

typedef __bf16 bf16x8 __attribute__((ext_vector_type(8)));
typedef float f32x16 __attribute__((ext_vector_type(16)));
typedef unsigned int u32x4 __attribute__((ext_vector_type(4)));

// row-XOR swizzle on 8-element groups (verified R2-R13)
__device__ __forceinline__ int swz(int r) { return ((r >> 1) ^ (r >> 4)) & 7; }

__device__ __forceinline__ void gld16(const void* gsrc, void* ldst) {
    __builtin_amdgcn_global_load_lds(
        (const __attribute__((address_space(1))) void*)gsrc,
        (__attribute__((address_space(3))) void*)ldst, 16, 0, 0);
}

// native 2^x
__device__ __forceinline__ float fexp2(float x) {
#if __has_builtin(__builtin_amdgcn_exp2f)
    return __builtin_amdgcn_exp2f(x);
#else
    return exp2f(x);
#endif
}

// pack two f32 -> dword of two bf16
__device__ __forceinline__ unsigned int pack2(float a, float b) {
    const unsigned short ua = __builtin_bit_cast(unsigned short, (__bf16)a);
    const unsigned short ub = __builtin_bit_cast(unsigned short, (__bf16)b);
    return (unsigned int)ua | ((unsigned int)ub << 16);
}

// ---------------- prepass: bake conversion + transpose + swizzle ----------------
// kt[b][m][c ^ (swz(m&63)<<3)]  (m-major: one 8KB contiguous block/tile)
// vt[b][c][t*64 + ((m&63) ^ (swz(c)<<3))]
__global__ __launch_bounds__(256)
void prepass(const float* __restrict__ yi, __bf16* __restrict__ kt,
             __bf16* __restrict__ vt)
{
    const int t = blockIdx.x;     // key tile 0..143
    const int b = blockIdx.y;
    const int tid = threadIdx.x;  // 256
    const float* src = yi + (size_t)b * CC * MM;

    for (int tsk = tid; tsk < 512; tsk += 256) {
        const int m = tsk & 63, g = tsk >> 6;
        const int m_abs = t * 64 + m;
        bf16x8 hh;
        #pragma unroll
        for (int j = 0; j < 8; ++j)
            hh[j] = (__bf16)src[(size_t)(g * 8 + j) * MM + m_abs];
        *reinterpret_cast<bf16x8*>(
            kt + (size_t)(b * MM + m_abs) * 64 + ((g ^ swz(m)) << 3)) = hh;
    }
    for (int tsk = tid; tsk < 512; tsk += 256) {
        const int c = tsk & 63, gm = tsk >> 6;
        const float* p = src + (size_t)c * MM + t * 64 + gm * 8;
        bf16x8 hh;
        #pragma unroll
        for (int j = 0; j < 8; ++j) hh[j] = (__bf16)p[j];
        *reinterpret_cast<bf16x8*>(
            vt + (size_t)(b * CC + c) * MM + t * 64 + ((gm ^ swz(c)) << 3)) = hh;
    }
}

// ---------------- main flash kernel (32x32x16, raw-2^s softmax, no max) ----------
template<bool FINAL>
__global__ __launch_bounds__(WAVES * 64, 2)
void attn_main(const __bf16* __restrict__ kt, const __bf16* __restrict__ vt,
               const float* __restrict__ pi,
               float* __restrict__ out, float* __restrict__ opart,
               float* __restrict__ lpart, const int nsplits)
{
    __shared__ __align__(16) __bf16 k_sm[2][MTILE][64];   // 16KB (double-buffered)
    __shared__ __align__(16) __bf16 v_sm[2][CC][64];      // 16KB  -> 32KB total

    const int tid  = threadIdx.x;
    const int lane = tid & 63;
    const int wave = tid >> 6;     // 0..3
    const int l31  = lane & 31;
    const int hi   = lane >> 5;    // 0/1

    // ---- block decode: XCD-locality map for 1D launches, else plain 3D ----
    int bx, split, b;
    if (gridDim.y == 1 && !FINAL) {
        const int bid = blockIdx.x;              // 0 .. 2*S*NBX-1
        const int xcd = bid & 7, slot = bid >> 3;
        bx = slot % NBX;
        const int g = xcd + 8 * (slot / NBX);    // group 0..2S-1, one XCD each
        split = g % nsplits;
        b     = g / nsplits;
    } else {
        bx = blockIdx.x; split = blockIdx.y; b = blockIdx.z;
    }

    const int tpb = NT / nsplits;
    const int t0s = split * tpb;
    const int n0  = bx * NBLK + wave * NPW;
    const int n_g = n0 + l31;

    // ---- async staging: 16 x 1KB chunks, 4 per wave, linear LDS dest ----
    auto stage = [&](int bb, int t) {
        const size_t kbase = (size_t)(b * MM + t * 64) * 64;   // elements
        #pragma unroll
        for (int q = 0; q < 4; ++q) {
            const int ch = wave * 4 + q;         // wave-uniform, 0..15
            if (ch < 8) {
                gld16(kt + kbase + ch * 512 + lane * 8,
                      (char*)(&k_sm[bb][0][0]) + ch * 1024);
            } else {
                const int j = ch - 8;
                const int c = j * 8 + (lane >> 3);
                gld16(vt + (size_t)(b * CC + c) * MM + t * 64 + (lane & 7) * 8,
                      (char*)(&v_sm[bb][0][0]) + j * 1024);
            }
        }
    };

    stage(0, t0s);   // DMA in flight while Q loads below

    // ---- Q fragments (hi/lo split), log2e folded in: s = log2e * (q.k) ----
    const float LOG2E = 1.4426950408889634f;
    bf16x8 qh[4], ql[4];
    {
        const float* qb = pi + (size_t)b * CC * MM + n_g;
        #pragma unroll
        for (int ks = 0; ks < 4; ++ks)
            #pragma unroll
            for (int j = 0; j < 8; ++j) {
                const float f = qb[(size_t)(ks * 16 + hi * 8 + j) * MM] * LOG2E;
                const __bf16 h = (__bf16)f;
                qh[ks][j] = h;
                ql[ks][j] = (__bf16)(f - (float)h);
            }
    }

    f32x16 o0, o1;
    #pragma unroll
    for (int r = 0; r < 16; ++r) { o0[r] = 0.f; o1[r] = 0.f; }
    float run_l = 0.f;

    const int sx0 = swz(l31) << 3;        // row swizzle, rows 0..31
    const int sx1 = swz(32 + l31) << 3;   // rows 32..63

    __syncthreads();   // vmcnt drained -> buf0 ready
    int buf = 0;

    for (int it = 0; it < tpb; ++it) {
        // ---- prefetch next tile into the other buffer; drains under compute ----
        if (it + 1 < tpb) stage(buf ^ 1, t0s + it + 1);

        // ---- QK^T: S[m 64][n 32], 2-product split-bf16 (K single-bf16) ----
        f32x16 s0, s1;
        #pragma unroll
        for (int r = 0; r < 16; ++r) { s0[r] = 0.f; s1[r] = 0.f; }
        __builtin_amdgcn_s_setprio(1);
        #pragma unroll
        for (int ks = 0; ks < 4; ++ks) {
            const int cb = ks * 16 + hi * 8;
            const bf16x8 a0 = *(const bf16x8*)&k_sm[buf][l31][cb ^ sx0];
            const bf16x8 a1 = *(const bf16x8*)&k_sm[buf][32 + l31][cb ^ sx1];
            s0 = __builtin_amdgcn_mfma_f32_32x32x16_bf16(a0, qh[ks], s0, 0, 0, 0);
            s1 = __builtin_amdgcn_mfma_f32_32x32x16_bf16(a1, qh[ks], s1, 0, 0, 0);
            s0 = __builtin_amdgcn_mfma_f32_32x32x16_bf16(a0, ql[ks], s0, 0, 0, 0);
            s1 = __builtin_amdgcn_mfma_f32_32x32x16_bf16(a1, ql[ks], s1, 0, 0, 0);
        }
        __builtin_amdgcn_s_setprio(0);

        // ---- raw softmax numerators: P = 2^s (no max tracking -- see R12) ----
        float ps[8];
        #pragma unroll
        for (int r = 0; r < 8; ++r) {
            s0[r]     = fexp2(s0[r]);
            s0[r + 8] = fexp2(s0[r + 8]);
            s1[r]     = fexp2(s1[r]);
            s1[r + 8] = fexp2(s1[r + 8]);
            ps[r] = (s0[r] + s0[r + 8]) + (s1[r] + s1[r + 8]);
        }
        float psum = ((ps[0] + ps[1]) + (ps[2] + ps[3])) +
                     ((ps[4] + ps[5]) + (ps[6] + ps[7]));
        psum += __shfl_xor(psum, 32);               // R6-verified reduce
        run_l += psum;

        // ---- pack P to bf16 dwords: X[mt][q][d] = pack(p[4q+2d], p[4q+2d+1]) ----
        unsigned int X[2][4][2];
        #pragma unroll
        for (int q = 0; q < 4; ++q)
            #pragma unroll
            for (int d = 0; d < 2; ++d) {
                X[0][q][d] = pack2(s0[4 * q + 2 * d], s0[4 * q + 2 * d + 1]);
                X[1][q][d] = pack2(s1[4 * q + 2 * d], s1[4 * q + 2 * d + 1]);
            }

        // ---- PV: B-frag via permlane32_swap (VALU; distinct operands) ----
        // rA = swap(A0,B0): rA[0] = {A0own | B0_partner}, rA[1] = {A0_partner | B0own}
        // == exactly the shfl_xor+select result for w.x / w.z (derived vs ISA).
        __builtin_amdgcn_s_setprio(1);
        #pragma unroll
        for (int ks = 0; ks < 4; ++ks) {
            const int mt = ks >> 1, e = ks & 1;
            auto rA = __builtin_amdgcn_permlane32_swap(
                X[mt][2 * e][0], X[mt][2 * e + 1][0], false, false);
            auto rB = __builtin_amdgcn_permlane32_swap(
                X[mt][2 * e][1], X[mt][2 * e + 1][1], false, false);
            u32x4 w;
            w.x = rA[0];   // j=0..1
            w.y = rB[0];   // j=2..3
            w.z = rA[1];   // j=4..5
            w.w = rB[1];   // j=6..7
            const bf16x8 bp = __builtin_bit_cast(bf16x8, w);

            const int cb = ks * 16 + hi * 8;
            const bf16x8 av0 = *(const bf16x8*)&v_sm[buf][l31][cb ^ sx0];
            const bf16x8 av1 = *(const bf16x8*)&v_sm[buf][32 + l31][cb ^ sx1];
            o0 = __builtin_amdgcn_mfma_f32_32x32x16_bf16(av0, bp, o0, 0, 0, 0);
            o1 = __builtin_amdgcn_mfma_f32_32x32x16_bf16(av1, bp, o1, 0, 0, 0);
        }
        __builtin_amdgcn_s_setprio(0);

        // ONE barrier: all waves done reading buf (it can be overwritten next
        // iter) AND the pre-barrier vmcnt drain publishes buf^1 for next iter.
        __syncthreads();
        buf ^= 1;
    }

    // ---- epilogue: c = (r&3) + 8*(r>>2) + 4*hi ----
    if (FINAL) {
        const float inv = 1.f / run_l;
        #pragma unroll
        for (int r = 0; r < 16; ++r) {
            const int cl = (r & 3) + 8 * (r >> 2) + 4 * hi;
            out[((size_t)b * CC + cl) * MM + n_g]      = o0[r] * inv;
            out[((size_t)b * CC + cl + 32) * MM + n_g] = o1[r] * inv;
        }
    } else {
        const size_t pbase = (size_t)(b * nsplits + split) * CC * MM;
        #pragma unroll
        for (int r = 0; r < 16; ++r) {
            const int cl = (r & 3) + 8 * (r >> 2) + 4 * hi;
            opart[pbase + (size_t)cl * MM + n_g]        = o0[r];
            opart[pbase + (size_t)(cl + 32) * MM + n_g] = o1[r];
        }
        if (hi == 0)   // lanes n and n+32 hold identical run_l
            lpart[(size_t)(b * nsplits + split) * MM + n_g] = run_l;
    }
}

// out = sum_s O_s / sum_s l_s  -- pure sums, no exp/max (shared zero baseline)
template<int S>
__global__ __launch_bounds__(256)
void attn_reduce4(const float* __restrict__ opart, const float* __restrict__ lpart,
                  float* __restrict__ out)
{
    const int t = blockIdx.x * 256 + threadIdx.x;
    if (t >= BB * CC * MM / 4) return;
    const int n  = (t * 4) % MM;
    const int bc = (t * 4) / MM;
    const int b  = bc / CC;
    const int c  = bc - b * CC;

    float L[4]   = {0.f, 0.f, 0.f, 0.f};
    float acc[4] = {0.f, 0.f, 0.f, 0.f};
    #pragma unroll
    for (int s = 0; s < S; ++s) {
        const float4 l4 = *reinterpret_cast<const float4*>(
            &lpart[(size_t)(b * S + s) * MM + n]);
        L[0] += l4.x; L[1] += l4.y; L[2] += l4.z; L[3] += l4.w;
        const float4 o4 = *reinterpret_cast<const float4*>(
            &opart[((size_t)(b * S + s) * CC + c) * MM + n]);
        acc[0] += o4.x; acc[1] += o4.y; acc[2] += o4.z; acc[3] += o4.w;
    }
    float4 r;
    r.x = acc[0] / L[0]; r.y = acc[1] / L[1];
    r.z = acc[2] / L[2]; r.w = acc[3] / L[3];
    *reinterpret_cast<float4*>(&out[(size_t)t * 4]) = r;
}

extern "C" void kernel_launch(void* const* d_in, const int* in_sizes, int n_in,
                              void* d_out, int out_size, void* d_ws, size_t ws_size,
                              hipStream_t stream) {
    const float* yi = (const float*)d_in[0];   // feature_yi (K = V)
    const float* pi = (const float*)d_in[1];   // feature_pi (Q)
    float* out = (float*)d_out;

    const size_t kelems = (size_t)BB * MM * 64;              // kt elements
    const size_t velems = (size_t)BB * CC * MM;              // vt elements
    const size_t preB   = (kelems + velems) * 2;             // ~4.7 MB
    auto need = [&](int s) -> size_t {
        return preB + (size_t)BB * s * CC * MM * 4 + (size_t)BB * s * MM * 4;
    };

    int S = 1;
    if (d_ws) {
        if (ws_size >= need(8))      S = 8;   // best total (R12/R13 A/B)
        else if (ws_size >= need(4)) S = 4;
        else if (ws_size >= need(2)) S = 2;
    }

    if (S == 1) {
        if (!d_ws || ws_size < preB) return;
        __bf16* kt = (__bf16*)d_ws;
        __bf16* vt = kt + kelems;
        prepass<<<dim3(NT, BB), dim3(256), 0, stream>>>(yi, kt, vt);
        attn_main<true><<<dim3(NBX, 1, BB), dim3(WAVES * 64), 0, stream>>>(
            kt, vt, pi, out, out, out, 1);
        return;
    }

    __bf16* kt   = (__bf16*)d_ws;
    __bf16* vt   = kt + kelems;
    float* opart = (float*)(vt + velems);
    float* lp    = opart + (size_t)BB * S * CC * MM;

    prepass<<<dim3(NT, BB), dim3(256), 0, stream>>>(yi, kt, vt);

    if (S == 8) {
        // 1D grid, XCD-locality mapping: all NBX n-blocks of a (b,split)
        // group land on one XCD (g = xcd + 8*(slot/NBX); bijective).
        attn_main<false><<<dim3(NBX * 2 * S), dim3(WAVES * 64), 0, stream>>>(
            kt, vt, pi, out, opart, lp, S);
    } else {
        attn_main<false><<<dim3(NBX, S, BB), dim3(WAVES * 64), 0, stream>>>(
            kt, vt, pi, out, opart, lp, S);
    }

    const int total4 = BB * CC * MM / 4;
    const dim3 rg((total4 + 255) / 256), rb(256);
    if (S == 8)      attn_reduce4<8><<<rg, rb, 0, stream>>>(opart, lp, out);
    else if (S == 4) attn_reduce4<4><<<rg, rb, 0, stream>>>(opart, lp, out);
    else             attn_reduce4<2><<<rg, rb, 0, stream>>>(opart, lp, out);
}

// Round 15
// 91.397 us; speedup vs baseline: 1.0991x; 1.0171x over previous
//
#include <hip/hip_runtime.h>
#include <hip/hip_bf16.h>

// Problem: B=2, C=64, H=W=96 -> M=N=9216
//   scores[b,m,n] = sum_c yi[b,c,m]*pi[b,c,n] ; weight = softmax over m
//   out[b,c,n]    = sum_m yi[b,c,m]*weight[b,m,n]
// == flash attention with Q=pi (queries n), K=V=yi (keys m), head dim 64.
//
// R15: R14 verified (93.0us total, main 83.2, absmax bit-exact as derived).
// Remaining safe margin is overhead, not structure:
//  (1) staging addresses hoisted out of the tile loop -- per-wave global
//      pointers bumped by constant stride (kt: 4096 elems, vt: 64) instead
//      of full recompute (~30 VALU/tile/wave saved);
//  (2) prepass grid x2 (576 blocks, half tasks each) -- it was latency-bound
//      at 1.1 blocks/CU, not BW-bound (~14MB moved).
// No arithmetic / sync / layout changes. Everything else byte-identical to
// R14 (verified): S=8 split-K, 32x32x16 MFMA, 2-product split-bf16 QK,
// raw-2^s softmax (no max -- score bound 92 log2-units << f32 range),
// permlane32_swap PV exchange, XCD-locality remap, dbuf + one barrier/tile.

#define CC 64
#define MM 9216
#define BB 2
#define WAVES 4
#define NPW 32                 // query columns per wave
#define NBLK (WAVES * NPW)     // 128
#define NBX (MM / NBLK)        // 72
#define MTILE 64
#define NT (MM / MTILE)        // 144

typedef __bf16 bf16x8 __attribute__((ext_vector_type(8)));
typedef float f32x16 __attribute__((ext_vector_type(16)));
typedef unsigned int u32x4 __attribute__((ext_vector_type(4)));

// row-XOR swizzle on 8-element groups (verified R2-R14)
__device__ __forceinline__ int swz(int r) { return ((r >> 1) ^ (r >> 4)) & 7; }

__device__ __forceinline__ void gld16(const void* gsrc, void* ldst) {
    __builtin_amdgcn_global_load_lds(
        (const __attribute__((address_space(1))) void*)gsrc,
        (__attribute__((address_space(3))) void*)ldst, 16, 0, 0);
}

// native 2^x
__device__ __forceinline__ float fexp2(float x) {
#if __has_builtin(__builtin_amdgcn_exp2f)
    return __builtin_amdgcn_exp2f(x);
#else
    return exp2f(x);
#endif
}

// pack two f32 -> dword of two bf16
__device__ __forceinline__ unsigned int pack2(float a, float b) {
    const unsigned short ua = __builtin_bit_cast(unsigned short, (__bf16)a);
    const unsigned short ub = __builtin_bit_cast(unsigned short, (__bf16)b);
    return (unsigned int)ua | ((unsigned int)ub << 16);
}

// ---------------- prepass: bake conversion + transpose + swizzle ----------------
// kt[b][m][c ^ (swz(m&63)<<3)]  (m-major: one 8KB contiguous block/tile)
// vt[b][c][t*64 + ((m&63) ^ (swz(c)<<3))]
// grid (NT*2, BB): blockIdx.x&1 selects task half (2.25 blocks/CU vs 1.1)
__global__ __launch_bounds__(256)
void prepass(const float* __restrict__ yi, __bf16* __restrict__ kt,
             __bf16* __restrict__ vt)
{
    const int t    = blockIdx.x >> 1;   // key tile 0..143
    const int half = blockIdx.x & 1;
    const int b    = blockIdx.y;
    const int tsk  = half * 256 + threadIdx.x;   // 0..511, one per block
    const float* src = yi + (size_t)b * CC * MM;

    {   // kt task
        const int m = tsk & 63, g = tsk >> 6;
        const int m_abs = t * 64 + m;
        bf16x8 hh;
        #pragma unroll
        for (int j = 0; j < 8; ++j)
            hh[j] = (__bf16)src[(size_t)(g * 8 + j) * MM + m_abs];
        *reinterpret_cast<bf16x8*>(
            kt + (size_t)(b * MM + m_abs) * 64 + ((g ^ swz(m)) << 3)) = hh;
    }
    {   // vt task
        const int c = tsk & 63, gm = tsk >> 6;
        const float* p = src + (size_t)c * MM + t * 64 + gm * 8;
        bf16x8 hh;
        #pragma unroll
        for (int j = 0; j < 8; ++j) hh[j] = (__bf16)p[j];
        *reinterpret_cast<bf16x8*>(
            vt + (size_t)(b * CC + c) * MM + t * 64 + ((gm ^ swz(c)) << 3)) = hh;
    }
}

// ---------------- main flash kernel (32x32x16, raw-2^s softmax, no max) ----------
template<bool FINAL>
__global__ __launch_bounds__(WAVES * 64, 2)
void attn_main(const __bf16* __restrict__ kt, const __bf16* __restrict__ vt,
               const float* __restrict__ pi,
               float* __restrict__ out, float* __restrict__ opart,
               float* __restrict__ lpart, const int nsplits)
{
    __shared__ __align__(16) __bf16 k_sm[2][MTILE][64];   // 16KB (double-buffered)
    __shared__ __align__(16) __bf16 v_sm[2][CC][64];      // 16KB  -> 32KB total

    const int tid  = threadIdx.x;
    const int lane = tid & 63;
    const int wave = tid >> 6;     // 0..3
    const int l31  = lane & 31;
    const int hi   = lane >> 5;    // 0/1

    // ---- block decode: XCD-locality map for 1D launches, else plain 3D ----
    int bx, split, b;
    if (gridDim.y == 1 && !FINAL) {
        const int bid = blockIdx.x;              // 0 .. 2*S*NBX-1
        const int xcd = bid & 7, slot = bid >> 3;
        bx = slot % NBX;
        const int g = xcd + 8 * (slot / NBX);    // group 0..2S-1, one XCD each
        split = g % nsplits;
        b     = g / nsplits;
    } else {
        bx = blockIdx.x; split = blockIdx.y; b = blockIdx.z;
    }

    const int tpb = NT / nsplits;
    const int t0s = split * tpb;
    const int n0  = bx * NBLK + wave * NPW;
    const int n_g = n0 + l31;

    // ---- staging state hoisted: per-wave global ptrs + fixed LDS dests ----
    // chunk ch = wave*4+q; ch<8 -> kt (stride 4096 elems/tile), else vt (64).
    const __bf16* gq[4];
    char* ld0[4];
    char* ld1[4];
    int gstep[4];
    #pragma unroll
    for (int q = 0; q < 4; ++q) {
        const int ch = wave * 4 + q;             // wave-uniform
        if (ch < 8) {
            gq[q]    = kt + (size_t)(b * MM + t0s * 64) * 64 + ch * 512 + lane * 8;
            gstep[q] = MTILE * 64;               // 4096 elements per tile
            ld0[q]   = (char*)(&k_sm[0][0][0]) + ch * 1024;
            ld1[q]   = (char*)(&k_sm[1][0][0]) + ch * 1024;
        } else {
            const int j = ch - 8;
            const int c = j * 8 + (lane >> 3);
            gq[q]    = vt + (size_t)(b * CC + c) * MM + t0s * 64 + (lane & 7) * 8;
            gstep[q] = MTILE;                    // 64 elements per tile
            ld0[q]   = (char*)(&v_sm[0][0][0]) + j * 1024;
            ld1[q]   = (char*)(&v_sm[1][0][0]) + j * 1024;
        }
    }
    auto stage = [&](int bb) {   // issues current tile's 4 chunks, bumps ptrs
        #pragma unroll
        for (int q = 0; q < 4; ++q) {
            gld16(gq[q], bb ? ld1[q] : ld0[q]);
            gq[q] += gstep[q];
        }
    };

    stage(0);   // tile t0s in flight while Q loads below

    // ---- Q fragments (hi/lo split), log2e folded in: s = log2e * (q.k) ----
    const float LOG2E = 1.4426950408889634f;
    bf16x8 qh[4], ql[4];
    {
        const float* qb = pi + (size_t)b * CC * MM + n_g;
        #pragma unroll
        for (int ks = 0; ks < 4; ++ks)
            #pragma unroll
            for (int j = 0; j < 8; ++j) {
                const float f = qb[(size_t)(ks * 16 + hi * 8 + j) * MM] * LOG2E;
                const __bf16 h = (__bf16)f;
                qh[ks][j] = h;
                ql[ks][j] = (__bf16)(f - (float)h);
            }
    }

    f32x16 o0, o1;
    #pragma unroll
    for (int r = 0; r < 16; ++r) { o0[r] = 0.f; o1[r] = 0.f; }
    float run_l = 0.f;

    const int sx0 = swz(l31) << 3;        // row swizzle, rows 0..31
    const int sx1 = swz(32 + l31) << 3;   // rows 32..63

    __syncthreads();   // vmcnt drained -> buf0 ready
    int buf = 0;

    for (int it = 0; it < tpb; ++it) {
        // ---- prefetch next tile into the other buffer; drains under compute ----
        if (it + 1 < tpb) stage(buf ^ 1);

        // ---- QK^T: S[m 64][n 32], 2-product split-bf16 (K single-bf16) ----
        f32x16 s0, s1;
        #pragma unroll
        for (int r = 0; r < 16; ++r) { s0[r] = 0.f; s1[r] = 0.f; }
        __builtin_amdgcn_s_setprio(1);
        #pragma unroll
        for (int ks = 0; ks < 4; ++ks) {
            const int cb = ks * 16 + hi * 8;
            const bf16x8 a0 = *(const bf16x8*)&k_sm[buf][l31][cb ^ sx0];
            const bf16x8 a1 = *(const bf16x8*)&k_sm[buf][32 + l31][cb ^ sx1];
            s0 = __builtin_amdgcn_mfma_f32_32x32x16_bf16(a0, qh[ks], s0, 0, 0, 0);
            s1 = __builtin_amdgcn_mfma_f32_32x32x16_bf16(a1, qh[ks], s1, 0, 0, 0);
            s0 = __builtin_amdgcn_mfma_f32_32x32x16_bf16(a0, ql[ks], s0, 0, 0, 0);
            s1 = __builtin_amdgcn_mfma_f32_32x32x16_bf16(a1, ql[ks], s1, 0, 0, 0);
        }
        __builtin_amdgcn_s_setprio(0);

        // ---- raw softmax numerators: P = 2^s (no max tracking -- see R12) ----
        float ps[8];
        #pragma unroll
        for (int r = 0; r < 8; ++r) {
            s0[r]     = fexp2(s0[r]);
            s0[r + 8] = fexp2(s0[r + 8]);
            s1[r]     = fexp2(s1[r]);
            s1[r + 8] = fexp2(s1[r + 8]);
            ps[r] = (s0[r] + s0[r + 8]) + (s1[r] + s1[r + 8]);
        }
        float psum = ((ps[0] + ps[1]) + (ps[2] + ps[3])) +
                     ((ps[4] + ps[5]) + (ps[6] + ps[7]));
        psum += __shfl_xor(psum, 32);               // R6-verified reduce
        run_l += psum;

        // ---- pack P to bf16 dwords: X[mt][q][d] = pack(p[4q+2d], p[4q+2d+1]) ----
        unsigned int X[2][4][2];
        #pragma unroll
        for (int q = 0; q < 4; ++q)
            #pragma unroll
            for (int d = 0; d < 2; ++d) {
                X[0][q][d] = pack2(s0[4 * q + 2 * d], s0[4 * q + 2 * d + 1]);
                X[1][q][d] = pack2(s1[4 * q + 2 * d], s1[4 * q + 2 * d + 1]);
            }

        // ---- PV: B-frag via permlane32_swap (VALU; distinct operands, R14-verified) ----
        __builtin_amdgcn_s_setprio(1);
        #pragma unroll
        for (int ks = 0; ks < 4; ++ks) {
            const int mt = ks >> 1, e = ks & 1;
            auto rA = __builtin_amdgcn_permlane32_swap(
                X[mt][2 * e][0], X[mt][2 * e + 1][0], false, false);
            auto rB = __builtin_amdgcn_permlane32_swap(
                X[mt][2 * e][1], X[mt][2 * e + 1][1], false, false);
            u32x4 w;
            w.x = rA[0];   // j=0..1
            w.y = rB[0];   // j=2..3
            w.z = rA[1];   // j=4..5
            w.w = rB[1];   // j=6..7
            const bf16x8 bp = __builtin_bit_cast(bf16x8, w);

            const int cb = ks * 16 + hi * 8;
            const bf16x8 av0 = *(const bf16x8*)&v_sm[buf][l31][cb ^ sx0];
            const bf16x8 av1 = *(const bf16x8*)&v_sm[buf][32 + l31][cb ^ sx1];
            o0 = __builtin_amdgcn_mfma_f32_32x32x16_bf16(av0, bp, o0, 0, 0, 0);
            o1 = __builtin_amdgcn_mfma_f32_32x32x16_bf16(av1, bp, o1, 0, 0, 0);
        }
        __builtin_amdgcn_s_setprio(0);

        // ONE barrier: all waves done reading buf (it can be overwritten next
        // iter) AND the pre-barrier vmcnt drain publishes buf^1 for next iter.
        __syncthreads();
        buf ^= 1;
    }

    // ---- epilogue: c = (r&3) + 8*(r>>2) + 4*hi ----
    if (FINAL) {
        const float inv = 1.f / run_l;
        #pragma unroll
        for (int r = 0; r < 16; ++r) {
            const int cl = (r & 3) + 8 * (r >> 2) + 4 * hi;
            out[((size_t)b * CC + cl) * MM + n_g]      = o0[r] * inv;
            out[((size_t)b * CC + cl + 32) * MM + n_g] = o1[r] * inv;
        }
    } else {
        const size_t pbase = (size_t)(b * nsplits + split) * CC * MM;
        #pragma unroll
        for (int r = 0; r < 16; ++r) {
            const int cl = (r & 3) + 8 * (r >> 2) + 4 * hi;
            opart[pbase + (size_t)cl * MM + n_g]        = o0[r];
            opart[pbase + (size_t)(cl + 32) * MM + n_g] = o1[r];
        }
        if (hi == 0)   // lanes n and n+32 hold identical run_l
            lpart[(size_t)(b * nsplits + split) * MM + n_g] = run_l;
    }
}

// out = sum_s O_s / sum_s l_s  -- pure sums, no exp/max (shared zero baseline)
template<int S>
__global__ __launch_bounds__(256)
void attn_reduce4(const float* __restrict__ opart, const float* __restrict__ lpart,
                  float* __restrict__ out)
{
    const int t = blockIdx.x * 256 + threadIdx.x;
    if (t >= BB * CC * MM / 4) return;
    const int n  = (t * 4) % MM;
    const int bc = (t * 4) / MM;
    const int b  = bc / CC;
    const int c  = bc - b * CC;

    float L[4]   = {0.f, 0.f, 0.f, 0.f};
    float acc[4] = {0.f, 0.f, 0.f, 0.f};
    #pragma unroll
    for (int s = 0; s < S; ++s) {
        const float4 l4 = *reinterpret_cast<const float4*>(
            &lpart[(size_t)(b * S + s) * MM + n]);
        L[0] += l4.x; L[1] += l4.y; L[2] += l4.z; L[3] += l4.w;
        const float4 o4 = *reinterpret_cast<const float4*>(
            &opart[((size_t)(b * S + s) * CC + c) * MM + n]);
        acc[0] += o4.x; acc[1] += o4.y; acc[2] += o4.z; acc[3] += o4.w;
    }
    float4 r;
    r.x = acc[0] / L[0]; r.y = acc[1] / L[1];
    r.z = acc[2] / L[2]; r.w = acc[3] / L[3];
    *reinterpret_cast<float4*>(&out[(size_t)t * 4]) = r;
}

extern "C" void kernel_launch(void* const* d_in, const int* in_sizes, int n_in,
                              void* d_out, int out_size, void* d_ws, size_t ws_size,
                              hipStream_t stream) {
    const float* yi = (const float*)d_in[0];   // feature_yi (K = V)
    const float* pi = (const float*)d_in[1];   // feature_pi (Q)
    float* out = (float*)d_out;

    const size_t kelems = (size_t)BB * MM * 64;              // kt elements
    const size_t velems = (size_t)BB * CC * MM;              // vt elements
    const size_t preB   = (kelems + velems) * 2;             // ~4.7 MB
    auto need = [&](int s) -> size_t {
        return preB + (size_t)BB * s * CC * MM * 4 + (size_t)BB * s * MM * 4;
    };

    int S = 1;
    if (d_ws) {
        if (ws_size >= need(8))      S = 8;   // best total (R12/R13 A/B)
        else if (ws_size >= need(4)) S = 4;
        else if (ws_size >= need(2)) S = 2;
    }

    if (S == 1) {
        if (!d_ws || ws_size < preB) return;
        __bf16* kt = (__bf16*)d_ws;
        __bf16* vt = kt + kelems;
        prepass<<<dim3(NT * 2, BB), dim3(256), 0, stream>>>(yi, kt, vt);
        attn_main<true><<<dim3(NBX, 1, BB), dim3(WAVES * 64), 0, stream>>>(
            kt, vt, pi, out, out, out, 1);
        return;
    }

    __bf16* kt   = (__bf16*)d_ws;
    __bf16* vt   = kt + kelems;
    float* opart = (float*)(vt + velems);
    float* lp    = opart + (size_t)BB * S * CC * MM;

    prepass<<<dim3(NT * 2, BB), dim3(256), 0, stream>>>(yi, kt, vt);

    if (S == 8) {
        // 1D grid, XCD-locality mapping: all NBX n-blocks of a (b,split)
        // group land on one XCD (g = xcd + 8*(slot/NBX); bijective).
        attn_main<false><<<dim3(NBX * 2 * S), dim3(WAVES * 64), 0, stream>>>(
            kt, vt, pi, out, opart, lp, S);
    } else {
        attn_main<false><<<dim3(NBX, S, BB), dim3(WAVES * 64), 0, stream>>>(
            kt, vt, pi, out, opart, lp, S);
    }

    const int total4 = BB * CC * MM / 4;
    const dim3 rg((total4 + 255) / 256), rb(256);
    if (S == 8)      attn_reduce4<8><<<rg, rb, 0, stream>>>(opart, lp, out);
    else if (S == 4) attn_reduce4<4><<<rg, rb, 0, stream>>>(opart, lp, out);
    else             attn_reduce4<2><<<rg, rb, 0, stream>>>(opart, lp, out);
}